// Round 1
// 1248.891 us; speedup vs baseline: 1.0770x; 1.0770x over previous
//
#include <hip/hip_runtime.h>

typedef __bf16 bf16x8 __attribute__((ext_vector_type(8)));
typedef float f32x16 __attribute__((ext_vector_type(16)));
typedef unsigned short ushort8 __attribute__((ext_vector_type(8)));

// ---------- helpers ----------
__device__ __forceinline__ float gelu_exact(float x) {
    return 0.5f * x * (1.0f + erff(x * 0.70710678118654752440f));
}

// ================= CSR build =================
__global__ __launch_bounds__(256) void count_kernel(
    const int* __restrict__ tgt, const int* __restrict__ src,
    int* __restrict__ cnt_i, int* __restrict__ cnt_a, int E)
{
    int e = blockIdx.x * 256 + threadIdx.x;
    if (e < E) {
        atomicAdd(&cnt_i[tgt[e]], 1);
        atomicAdd(&cnt_a[src[e]], 1);
    }
}

__global__ __launch_bounds__(256) void scan_block(
    const int* __restrict__ cnt, int* __restrict__ offs, int* __restrict__ bsum, int N)
{
    __shared__ int s[256];
    int i = blockIdx.x * 256 + threadIdx.x;
    int v = (i < N) ? cnt[i] : 0;
    s[threadIdx.x] = v;
    __syncthreads();
    for (int d = 1; d < 256; d <<= 1) {
        int t = (threadIdx.x >= d) ? s[threadIdx.x - d] : 0;
        __syncthreads();
        s[threadIdx.x] += t;
        __syncthreads();
    }
    if (i < N) offs[i] = s[threadIdx.x] - v;   // exclusive
    if (threadIdx.x == 255) bsum[blockIdx.x] = s[255];
}

__global__ __launch_bounds__(256) void scan_bsum(int* __restrict__ bsum, int nb)
{
    __shared__ int s[256];
    int v = (threadIdx.x < nb) ? bsum[threadIdx.x] : 0;
    s[threadIdx.x] = v;
    __syncthreads();
    for (int d = 1; d < 256; d <<= 1) {
        int t = (threadIdx.x >= d) ? s[threadIdx.x - d] : 0;
        __syncthreads();
        s[threadIdx.x] += t;
        __syncthreads();
    }
    if (threadIdx.x < nb) bsum[threadIdx.x] = s[threadIdx.x] - v;  // exclusive
}

__global__ __launch_bounds__(256) void add_offs(
    int* __restrict__ offs, int* __restrict__ cursor,
    const int* __restrict__ bsum, int N, int E)
{
    int i = blockIdx.x * 256 + threadIdx.x;
    if (i < N) {
        int f = offs[i] + bsum[blockIdx.x];
        offs[i] = f;
        cursor[i] = f;
    }
    if (i == 0) offs[N] = E;
}

__global__ __launch_bounds__(256) void fill_kernel(
    const int* __restrict__ tgt, const int* __restrict__ src,
    int* __restrict__ cur_i, int* __restrict__ cur_a,
    int* __restrict__ eid_i, int* __restrict__ eid_a, int E)
{
    int e = blockIdx.x * 256 + threadIdx.x;
    if (e < E) {
        int p = atomicAdd(&cur_i[tgt[e]], 1);
        eid_i[p] = e;
        int q = atomicAdd(&cur_a[src[e]], 1);
        eid_a[q] = e;
    }
}

// ================= weight prep: f32 W[K][256] -> bf16 hi/lo, transposed [256][K] =================
struct PrepArgs {
    const float* src[7];
    unsigned short* hi[7];
    unsigned short* lo[7];
    int K[7];
    int off[8];   // block offsets (blocks per matrix = K)
};

__global__ __launch_bounds__(256) void prep_all(PrepArgs a)
{
    int b = blockIdx.x;
    int m = 0;
    #pragma unroll
    for (int i = 0; i < 6; ++i) m += (b >= a.off[i + 1]) ? 1 : 0;
    int K = a.K[m];
    int idx = (b - a.off[m]) * 256 + threadIdx.x;
    if (idx >= K * 256) return;
    int k = idx >> 8;       // N = 256
    int n = idx & 255;
    float x = a.src[m][idx];
    __bf16 h = (__bf16)x;
    __bf16 l = (__bf16)(x - (float)h);
    a.hi[m][(size_t)n * K + k] = __builtin_bit_cast(unsigned short, h);
    a.lo[m][(size_t)n * K + k] = __builtin_bit_cast(unsigned short, l);
}

// ================= fused per-target attention (unchanged) =================
__global__ __launch_bounds__(256) void fused_attn(
    const float* __restrict__ Q, const float* __restrict__ Kk, const float* __restrict__ V,
    const int* __restrict__ offs, const int* __restrict__ eids,
    const int* __restrict__ other, const float* __restrict__ nw,
    float* __restrict__ scbuf, float* __restrict__ msg, int T)
{
    int w = blockIdx.x * 4 + (threadIdx.x >> 6);
    int lane = threadIdx.x & 63;
    if (w >= T) return;
    int t = w;
    int beg = offs[t], end = offs[t + 1];
    int h = lane >> 4;

    float4 q = *(const float4*)(Q + (size_t)t * 256 + lane * 4);

    float mx = 0.f;
    for (int j = beg; j < end; ++j) {
        int e = eids[j];
        int s = other[e];
        float4 k = *(const float4*)(Kk + (size_t)s * 256 + lane * 4);
        float d = q.x * k.x + q.y * k.y + q.z * k.z + q.w * k.w;
        d += __shfl_xor(d, 1);
        d += __shfl_xor(d, 2);
        d += __shfl_xor(d, 4);
        d += __shfl_xor(d, 8);
        float sc = d * 0.125f + logf(fmaxf(nw[e], 1e-10f));
        if ((lane & 15) == 0) scbuf[(size_t)j * 4 + h] = sc;
        mx = fmaxf(mx, sc);
    }

    float sum = 0.f;
    float4 macc = make_float4(0.f, 0.f, 0.f, 0.f);
    for (int j = beg; j < end; ++j) {
        int e = eids[j];
        int s = other[e];
        float sc = scbuf[(size_t)j * 4 + h];
        float ex = expf(sc - mx);
        sum += ex;
        float4 v = *(const float4*)(V + (size_t)s * 256 + lane * 4);
        macc.x += ex * v.x; macc.y += ex * v.y;
        macc.z += ex * v.z; macc.w += ex * v.w;
    }
    float inv = 1.f / (sum + 1e-10f);
    *(float4*)(msg + (size_t)t * 256 + lane * 4) =
        make_float4(macc.x * inv, macc.y * inv, macc.z * inv, macc.w * inv);
}

// ================= MFMA bf16x3 GEMM =================
// C[M,256] = act(concat(A1,A2)[M,K] @ W[K,256] + bias)
// W pre-split/transposed: Whi/Wlo are [256][K] bf16 (row n holds column n of W).
// Block 128x128, 4 waves 2x2, wave tile 64x64 = 2x2 subtiles of 32x32.
// mfma_f32_32x32x16_bf16: A[l&31][(l>>5)*8+i], B[(l>>5)*8+i][l&31],
//                         C/D: col=l&31, row=(r&3)+8*(r>>2)+4*(l>>5).
// No LDS: A frags loaded f32 from global and split hi/lo in regs (VALU hides under MFMA);
// B frags are direct 16B loads from L2-resident pre-split weights.
template<int CONCAT>
__global__ __launch_bounds__(256) void gemm_mfma(
    const float* __restrict__ A1, const float* __restrict__ A2,
    const unsigned short* __restrict__ Whi, const unsigned short* __restrict__ Wlo,
    const float* __restrict__ bias, float* __restrict__ C, int M, int act)
{
    const int K = CONCAT ? 512 : 256;
    const int lane = threadIdx.x & 63;
    const int wv = threadIdx.x >> 6;
    const int wm = wv >> 1, wn = wv & 1;
    const int bm = blockIdx.y * 128;
    const int bn = blockIdx.x * 128;

    const int lr = lane & 31;          // row (A) / col (B,C) within 32-subtile
    const int kg = (lane >> 5) << 3;   // k-group offset: 0 or 8

    f32x16 acc[2][2] = {};

    const int arow0 = bm + wm * 64 + lr;
    const int bcol0 = bn + wn * 64 + lr;

    for (int part = 0; part < (CONCAT ? 2 : 1); ++part) {
        const float* Ap = part ? A2 : A1;
        const int kb = part << 8;
        #pragma unroll 2
        for (int k0 = 0; k0 < 256; k0 += 16) {
            // ---- A fragments: global f32 -> hi/lo bf16 in regs ----
            bf16x8 ah[2], al[2];
            #pragma unroll
            for (int mt = 0; mt < 2; ++mt) {
                int row = arow0 + mt * 32;
                float4 f0 = make_float4(0.f, 0.f, 0.f, 0.f), f1 = f0;
                if (row < M) {
                    const float* p = Ap + (size_t)row * 256 + k0 + kg;
                    f0 = *(const float4*)p;
                    f1 = *(const float4*)(p + 4);
                }
                float xs[8] = {f0.x, f0.y, f0.z, f0.w, f1.x, f1.y, f1.z, f1.w};
                #pragma unroll
                for (int i = 0; i < 8; ++i) {
                    __bf16 h = (__bf16)xs[i];
                    ah[mt][i] = h;
                    al[mt][i] = (__bf16)(xs[i] - (float)h);
                }
            }
            // ---- B fragments: pre-split transposed weights ----
            bf16x8 bh[2], bl[2];
            #pragma unroll
            for (int nt = 0; nt < 2; ++nt) {
                size_t o = (size_t)(bcol0 + nt * 32) * K + kb + k0 + kg;
                bh[nt] = __builtin_bit_cast(bf16x8, *(const ushort8*)(Whi + o));
                bl[nt] = __builtin_bit_cast(bf16x8, *(const ushort8*)(Wlo + o));
            }
            // ---- bf16x3: hi*hi + hi*lo + lo*hi (f32 accumulate) ----
            #pragma unroll
            for (int mt = 0; mt < 2; ++mt)
            #pragma unroll
            for (int nt = 0; nt < 2; ++nt) {
                acc[mt][nt] = __builtin_amdgcn_mfma_f32_32x32x16_bf16(ah[mt], bh[nt], acc[mt][nt], 0, 0, 0);
                acc[mt][nt] = __builtin_amdgcn_mfma_f32_32x32x16_bf16(ah[mt], bl[nt], acc[mt][nt], 0, 0, 0);
                acc[mt][nt] = __builtin_amdgcn_mfma_f32_32x32x16_bf16(al[mt], bh[nt], acc[mt][nt], 0, 0, 0);
            }
        }
    }

    // ---- epilogue: bias + GELU + store ----
    #pragma unroll
    for (int mt = 0; mt < 2; ++mt)
    #pragma unroll
    for (int nt = 0; nt < 2; ++nt) {
        int col = bn + wn * 64 + nt * 32 + lr;
        int rbase = bm + wm * 64 + mt * 32 + ((lane >> 5) << 2);
        float bv = bias ? bias[col] : 0.f;
        #pragma unroll
        for (int r = 0; r < 16; ++r) {
            int row = rbase + (r & 3) + ((r >> 2) << 3);
            if (row < M) {
                float v = acc[mt][nt][r] + bv;
                if (act) v = gelu_exact(v);
                C[(size_t)row * 256 + col] = v;
            }
        }
    }
}

// ================= host =================
extern "C" void kernel_launch(void* const* d_in, const int* in_sizes, int n_in,
                              void* d_out, int out_size, void* d_ws, size_t ws_size,
                              hipStream_t stream) {
    const float* inv_h    = (const float*)d_in[0];
    const float* asset_h  = (const float*)d_in[1];
    const float* inv_nw   = (const float*)d_in[2];
    const float* asset_nw = (const float*)d_in[3];
    const float* m_w1 = (const float*)d_in[4];
    const float* m_b1 = (const float*)d_in[5];
    const float* m_w2 = (const float*)d_in[6];
    const float* m_b2 = (const float*)d_in[7];
    const float* Wq   = (const float*)d_in[8];
    const float* Wk   = (const float*)d_in[9];
    const float* Wv   = (const float*)d_in[10];
    const float* u_w1 = (const float*)d_in[11];
    const float* u_b1 = (const float*)d_in[12];
    const float* u_w2 = (const float*)d_in[13];
    const float* u_b2 = (const float*)d_in[14];
    const int* etgt  = (const int*)d_in[15];
    const int* esrc  = (const int*)d_in[16];

    const int I = in_sizes[0] / 256;
    const int A = in_sizes[1] / 256;
    const int E = in_sizes[15];

    float* out_inv   = (float*)d_out;
    float* out_asset = (float*)d_out + (size_t)I * 256;

    char* wsp = (char*)d_ws;
    size_t off = 0;
    auto alloc = [&](size_t bytes) -> void* {
        void* p = wsp + off;
        off += (bytes + 255) & ~(size_t)255;
        return p;
    };
    float* X1 = (float*)alloc((size_t)I * 256 * 4);
    float* X2 = (float*)alloc((size_t)I * 256 * 4);
    float* Y1 = (float*)alloc((size_t)A * 256 * 4);
    float* Y2 = (float*)alloc((size_t)A * 256 * 4);
    float* msg_a = (float*)alloc((size_t)A * 256 * 4);
    float* scbuf = (float*)alloc((size_t)E * 4 * 4);
    int* cnt_i  = (int*)alloc((size_t)I * 4);
    int* cnt_a  = (int*)alloc((size_t)A * 4);
    int* offs_i = (int*)alloc((size_t)(I + 1) * 4);
    int* offs_a = (int*)alloc((size_t)(A + 1) * 4);
    int* eid_i  = (int*)alloc((size_t)E * 4);
    int* eid_a  = (int*)alloc((size_t)E * 4);
    int* bsum_i = (int*)alloc(256 * 4);
    int* bsum_a = (int*)alloc(256 * 4);
    float* msg_i = X2;   // overlays X2 (K_i dead before msg_i written)

    // pre-split weights (hi/lo bf16, transposed [N=256][K])
    PrepArgs pa;
    const float* wsrc[7] = {m_w1, m_w2, Wq, Wk, Wv, u_w1, u_w2};
    const int    wK[7]   = {256, 256, 256, 256, 256, 512, 256};
    unsigned short* whi[7];
    unsigned short* wlo[7];
    pa.off[0] = 0;
    for (int i = 0; i < 7; ++i) {
        whi[i] = (unsigned short*)alloc((size_t)wK[i] * 256 * 2);
        wlo[i] = (unsigned short*)alloc((size_t)wK[i] * 256 * 2);
        pa.src[i] = wsrc[i];
        pa.hi[i] = whi[i];
        pa.lo[i] = wlo[i];
        pa.K[i] = wK[i];
        pa.off[i + 1] = pa.off[i] + wK[i];
    }

    const int nbI = (I + 255) / 256;
    const int nbA = (A + 255) / 256;
    const int nbE = (E + 255) / 256;

    // ---- weight prep (independent of CSR) ----
    hipLaunchKernelGGL(prep_all, dim3(pa.off[7]), dim3(256), 0, stream, pa);

    // ---- CSR build (both directions) ----
    hipMemsetAsync(cnt_i, 0, ((size_t)I + A) * 4 + 256 - 256, stream);
    hipMemsetAsync(cnt_a, 0, (size_t)A * 4, stream);
    hipLaunchKernelGGL(count_kernel, dim3(nbE), dim3(256), 0, stream,
                       etgt, esrc, cnt_i, cnt_a, E);
    hipLaunchKernelGGL(scan_block, dim3(nbI), dim3(256), 0, stream, cnt_i, offs_i, bsum_i, I);
    hipLaunchKernelGGL(scan_block, dim3(nbA), dim3(256), 0, stream, cnt_a, offs_a, bsum_a, A);
    hipLaunchKernelGGL(scan_bsum, dim3(1), dim3(256), 0, stream, bsum_i, nbI);
    hipLaunchKernelGGL(scan_bsum, dim3(1), dim3(256), 0, stream, bsum_a, nbA);
    hipLaunchKernelGGL(add_offs, dim3(nbI), dim3(256), 0, stream, offs_i, cnt_i, bsum_i, I, E);
    hipLaunchKernelGGL(add_offs, dim3(nbA), dim3(256), 0, stream, offs_a, cnt_a, bsum_a, A, E);
    hipLaunchKernelGGL(fill_kernel, dim3(nbE), dim3(256), 0, stream,
                       etgt, esrc, cnt_i, cnt_a, eid_i, eid_a, E);

    auto gemm = [&](const float* A1p, const float* A2p, int M, int widx,
                    const float* bias, float* Cm, int act, int concat) {
        dim3 grid(2, (M + 127) / 128);
        if (concat) hipLaunchKernelGGL((gemm_mfma<1>), grid, dim3(256), 0, stream,
                                       A1p, A2p, whi[widx], wlo[widx], bias, Cm, M, act);
        else        hipLaunchKernelGGL((gemm_mfma<0>), grid, dim3(256), 0, stream,
                                       A1p, A2p, whi[widx], wlo[widx], bias, Cm, M, act);
    };
    // widx: 0=m_w1 1=m_w2 2=Wq 3=Wk 4=Wv 5=u_w1 6=u_w2

    // ===== direction 2: assets aggregate from investors (segments = esrc) =====
    gemm(inv_h, nullptr, I, 0, m_b1, X1, 1, 0);     // t_i
    gemm(X1,    nullptr, I, 1, m_b2, X2, 1, 0);     // M_i
    gemm(X2,    nullptr, I, 4, nullptr, X1, 0, 0);  // V_i
    gemm(inv_h, nullptr, I, 3, nullptr, X2, 0, 0);  // K_i
    gemm(asset_h, nullptr, A, 2, nullptr, Y1, 0, 0);// Q_a

    hipLaunchKernelGGL(fused_attn, dim3((A + 3) / 4), dim3(256), 0, stream,
                       Y1, X2, X1, offs_a, eid_a, etgt, asset_nw, scbuf, msg_a, A);

    gemm(asset_h, msg_a, A, 5, u_b1, Y2, 1, 1);     // hid_a
    gemm(Y2, nullptr, A, 6, u_b2, out_asset, 1, 0);

    // ===== direction 1: investors aggregate from assets (segments = etgt) =====
    gemm(asset_h, nullptr, A, 0, m_b1, Y1, 1, 0);   // t_a
    gemm(Y1,      nullptr, A, 1, m_b2, Y2, 1, 0);   // M_a
    gemm(Y2,      nullptr, A, 4, nullptr, Y1, 0, 0);// V_a
    gemm(asset_h, nullptr, A, 3, nullptr, Y2, 0, 0);// K_a
    gemm(inv_h,   nullptr, I, 2, nullptr, X1, 0, 0);// Q_i

    hipLaunchKernelGGL(fused_attn, dim3((I + 3) / 4), dim3(256), 0, stream,
                       X1, Y2, Y1, offs_i, eid_i, esrc, inv_nw, scbuf, msg_i, I);

    gemm(inv_h, msg_i, I, 5, u_b1, X1, 1, 1);       // hid_i
    gemm(X1, nullptr, I, 6, u_b2, out_inv, 1, 0);
}